// Round 1
// baseline (3254.422 us; speedup 1.0000x reference)
//
#include <hip/hip_runtime.h>
#include <cstdint>
#include <cstddef>

#define N_ANCH 20000
#define N_CLS  80
#define MAXDET 300
#define NMS_T  512
#define ELEMS  40  // ceil(N_ANCH / NMS_T)

// One block per (image, class). Greedy NMS, bit-exact vs numpy/JAX fp32:
// unfused IEEE ops, argmax tie-break = lowest index.
__global__ __launch_bounds__(NMS_T)
void nms_kernel(const float* __restrict__ boxes,
                const float* __restrict__ cls,
                uint4* __restrict__ picks)
{
  const int bc  = blockIdx.x;
  const int b   = bc / N_CLS;
  const int c   = bc - b * N_CLS;
  const int tid = threadIdx.x;

  const float4* boxesB = reinterpret_cast<const float4*>(boxes) + (size_t)b * N_ANCH;
  const float*  clsB   = cls + ((size_t)b * N_ANCH) * N_CLS + c;

  // Thresholded scores live in registers: 40 per thread, statically indexed.
  float sc[ELEMS];
  float lv = -INFINITY;
  int   li = 0;
#pragma unroll
  for (int k = 0; k < ELEMS; ++k) {
    const int j = tid + (k << 9);
    float v = -INFINITY;
    if (j < N_ANCH) {
      const float t = clsB[(size_t)j * N_CLS];
      v = (t > 0.05f) ? t : -INFINITY;
    }
    sc[k] = v;
    if (v > lv) { lv = v; li = j; }  // ascending j scan keeps first max on ties
  }

  __shared__ float rv[NMS_T / 64];
  __shared__ int   ri[NMS_T / 64];

  int it = 0;
  for (; it < MAXDET; ++it) {
    // ---- block argmax of (lv, li), tie -> smaller index ----
    float v = lv; int i = li;
#pragma unroll
    for (int off = 32; off > 0; off >>= 1) {
      const float ov = __shfl_xor(v, off);
      const int   oi = __shfl_xor(i, off);
      if (ov > v || (ov == v && oi < i)) { v = ov; i = oi; }
    }
    const int wid = tid >> 6;
    if ((tid & 63) == 0) { rv[wid] = v; ri[wid] = i; }
    __syncthreads();  // (1) rv/ri ready

    float selVal = rv[0];
    int   selIdx = ri[0];
#pragma unroll
    for (int w = 1; w < NMS_T / 64; ++w) {
      const float ov = rv[w]; const int oi = ri[w];
      if (ov > selVal || (ov == selVal && oi < selIdx)) { selVal = ov; selIdx = oi; }
    }

    if (!(selVal > -INFINITY)) break;  // nothing left above threshold

    if (tid == 0) {
      // key: descending score, tie -> ascending flat position (c*300 + it).
      const unsigned long long key =
          ((unsigned long long)__float_as_uint(selVal) << 32) |
          (unsigned long long)(0xFFFFFFFFu - (unsigned)(c * MAXDET + it));
      picks[(size_t)bc * MAXDET + it] =
          make_uint4((unsigned)(key & 0xFFFFFFFFull), (unsigned)(key >> 32),
                     (unsigned)selIdx, 0u);
    }

    const float4 sb = boxesB[selIdx];  // uniform address -> single line
    const float selArea = __fmul_rn(__fsub_rn(sb.z, sb.x), __fsub_rn(sb.w, sb.y));

    // ---- suppression pass + next local argmax (fused) ----
    // Note: the selected element sees IOU == 1.0 with itself and self-suppresses,
    // so no cross-thread score write is needed anywhere.
    lv = -INFINITY; li = 0;
#pragma unroll
    for (int k = 0; k < ELEMS; ++k) {
      const float vv = sc[k];
      if (vv > -INFINITY) {
        const int j = tid + (k << 9);
        const float4 bb = boxesB[j];
        const float xx1 = fmaxf(bb.x, sb.x);
        const float yy1 = fmaxf(bb.y, sb.y);
        const float xx2 = fminf(bb.z, sb.z);
        const float yy2 = fminf(bb.w, sb.w);
        const float iw  = fmaxf(__fsub_rn(xx2, xx1), 0.0f);
        const float ih  = fmaxf(__fsub_rn(yy2, yy1), 0.0f);
        const float inter = __fmul_rn(iw, ih);
        const float aj    = __fmul_rn(__fsub_rn(bb.z, bb.x), __fsub_rn(bb.w, bb.y));
        const float denom = __fsub_rn(__fadd_rn(aj, selArea), inter);
        const float iou   = __fdiv_rn(inter, denom);
        if (iou > 0.5f) {
          sc[k] = -INFINITY;
        } else if (vv > lv) {
          lv = vv; li = j;
        }
      }
    }
    __syncthreads();  // (2) protect rv/ri reads of this iter vs writes of next
  }

  // Invalid tail (valid == false in the reference): key 0 sentinel.
  for (int r = it + tid; r < MAXDET; r += NMS_T) {
    picks[(size_t)bc * MAXDET + r] = make_uint4(0u, 0u, 0u, 0u);
  }
}

// One wave per image: exact 80-way merge of the per-class descending pick
// lists (= jax.lax.top_k over the 24000 candidates, stable tie-break via key).
__global__ __launch_bounds__(64)
void topk_merge_kernel(const uint4* __restrict__ picks,
                       const float* __restrict__ boxes,
                       float* __restrict__ out, int B)
{
  const int b    = blockIdx.x;
  const int lane = threadIdx.x;

  const int clsa = lane;        // classes 0..63
  const int clsb = 64 + lane;   // classes 64..79 on lanes 0..15

  unsigned long long k0a = 0, k1a = 0, k0b = 0, k1b = 0;
  unsigned a0a = 0, a1a = 0, a0b = 0, a1b = 0;
  int ma = 2, mb = 2;

  {
    const uint4* base = picks + (size_t)(b * N_CLS + clsa) * MAXDET;
    const uint4 e0 = base[0], e1 = base[1];
    k0a = ((unsigned long long)e0.y << 32) | e0.x; a0a = e0.z;
    k1a = ((unsigned long long)e1.y << 32) | e1.x; a1a = e1.z;
  }
  if (clsb < N_CLS) {
    const uint4* base = picks + (size_t)(b * N_CLS + clsb) * MAXDET;
    const uint4 e0 = base[0], e1 = base[1];
    k0b = ((unsigned long long)e0.y << 32) | e0.x; a0b = e0.z;
    k1b = ((unsigned long long)e1.y << 32) | e1.x; a1b = e1.z;
  }

  float* outBoxes  = out;                               // [B,300,4]
  float* outScores = out + (size_t)B * MAXDET * 4;      // [B,300]
  float* outLabels = out + (size_t)B * MAXDET * 5;      // [B,300] (as float)

  for (int r = 0; r < MAXDET; ++r) {
    unsigned long long myk = k0a; int mycls = clsa; unsigned mya = a0a;
    if (k0b > myk) { myk = k0b; mycls = clsb; mya = a0b; }
#pragma unroll
    for (int off = 32; off > 0; off >>= 1) {
      const unsigned long long ok = __shfl_xor(myk, off);
      const int      ocls = __shfl_xor(mycls, off);
      const unsigned oa   = __shfl_xor(mya, off);
      if (ok > myk) { myk = ok; mycls = ocls; mya = oa; }
    }
    // all lanes now hold the winner (keys are unique except the 0 sentinel)

    if (lane == 0) {
      const size_t o = (size_t)b * MAXDET + r;
      if (myk == 0ull) {
        reinterpret_cast<float4*>(outBoxes)[o] = make_float4(-1.f, -1.f, -1.f, -1.f);
        outScores[o] = -1.f;
        outLabels[o] = -1.f;
      } else {
        const float4 bb =
            reinterpret_cast<const float4*>(boxes)[(size_t)b * N_ANCH + mya];
        reinterpret_cast<float4*>(outBoxes)[o] = bb;
        outScores[o] = __uint_as_float((unsigned)(myk >> 32));
        outLabels[o] = (float)mycls;
      }
    }

    if (myk != 0ull) {  // advance the winning class's head (owner lane only)
      const int owner = mycls & 63;
      if (lane == owner) {
        if (mycls < 64) {
          k0a = k1a; a0a = a1a;
          if (ma < MAXDET) {
            const uint4 e = picks[(size_t)(b * N_CLS + mycls) * MAXDET + ma];
            k1a = ((unsigned long long)e.y << 32) | e.x; a1a = e.z; ++ma;
          } else k1a = 0ull;
        } else {
          k0b = k1b; a0b = a1b;
          if (mb < MAXDET) {
            const uint4 e = picks[(size_t)(b * N_CLS + mycls) * MAXDET + mb];
            k1b = ((unsigned long long)e.y << 32) | e.x; a1b = e.z; ++mb;
          } else k1b = 0ull;
        }
      }
    }
  }
}

extern "C" void kernel_launch(void* const* d_in, const int* in_sizes, int n_in,
                              void* d_out, int out_size, void* d_ws, size_t ws_size,
                              hipStream_t stream)
{
  const float* boxes = (const float*)d_in[0];
  const float* cls   = (const float*)d_in[1];
  const int B = in_sizes[0] / (N_ANCH * 4);  // = 2

  // workspace: picks[B*C][300] as uint4 {key_lo, key_hi, anchor, pad} = 768 KB
  uint4* picks = (uint4*)d_ws;

  nms_kernel<<<dim3(B * N_CLS), dim3(NMS_T), 0, stream>>>(boxes, cls, picks);
  topk_merge_kernel<<<dim3(B), dim3(64), 0, stream>>>(picks, boxes, (float*)d_out, B);
}

// Round 2
// 662.267 us; speedup vs baseline: 4.9141x; 4.9141x over previous
//
#include <hip/hip_runtime.h>
#include <cstdint>
#include <cstddef>

#define N_ANCH 20000
#define N_CLS  80
#define MAXDET 300
#define NMS_T  512
#define ELEMS  40      // ceil(N_ANCH / NMS_T)
#define SORTN  4096    // bitonic sort size (pow2)
#define KSEL   3072    // target top-K per selection round
#define NB     1024    // histogram buckets (564 used; pow2 for scan)
#define BUCKET_BASE 0x3D4C  // float bits of ~0.05 >> 16

__device__ __forceinline__ float box_area(float4 b) {
  return __fmul_rn(__fsub_rn(b.z, b.x), __fsub_rn(b.w, b.y));
}

// IOU, unfused IEEE ops, exactly the reference's association order.
__device__ __forceinline__ bool iou_gt_half(float4 a, float aa, float4 b, float ab) {
  const float xx1 = fmaxf(a.x, b.x);
  const float yy1 = fmaxf(a.y, b.y);
  const float xx2 = fminf(a.z, b.z);
  const float yy2 = fminf(a.w, b.w);
  const float iw  = fmaxf(__fsub_rn(xx2, xx1), 0.0f);
  const float ih  = fmaxf(__fsub_rn(yy2, yy1), 0.0f);
  const float inter = __fmul_rn(iw, ih);
  const float denom = __fsub_rn(__fadd_rn(aa, ab), inter);
  return __fdiv_rn(inter, denom) > 0.5f;
}

// One block per (image, class). Sorted-candidate greedy NMS (exact):
// a candidate is suppressed iff IOU>0.5 with an already-picked box.
__global__ __launch_bounds__(NMS_T)
void nms_kernel(const float* __restrict__ boxes,
                const float* __restrict__ cls,
                uint4* __restrict__ picks)
{
  const int bc  = blockIdx.x;
  const int b   = bc / N_CLS;
  const int c   = bc - b * N_CLS;
  const int tid = threadIdx.x;

  const float4* boxesB = reinterpret_cast<const float4*>(boxes) + (size_t)b * N_ANCH;
  const float*  clsB   = cls + ((size_t)b * N_ANCH) * N_CLS + c;

  __shared__ unsigned long long keys[SORTN];   // 32 KB
  __shared__ unsigned histo[NB];               // 4 KB (becomes suffix-sum)
  __shared__ int sh_cnt, sh_np, sh_bt;

  for (int i = tid; i < NB; i += NMS_T) histo[i] = 0;
  __syncthreads();

  // ---- Phase 1: read scores (cached in regs), build histogram ----
  float sc[ELEMS];
#pragma unroll
  for (int k = 0; k < ELEMS; ++k) {
    const int j = tid + (k << 9);
    float v = -1.0f;
    if (j < N_ANCH) {
      const float t = clsB[(size_t)j * N_CLS];
      if (t > 0.05f) v = t;
    }
    sc[k] = v;
    if (v > 0.0f) {
      const int bk = (int)(__float_as_uint(v) >> 16) - BUCKET_BASE;
      atomicAdd(&histo[bk], 1u);
    }
  }
  __syncthreads();

  // ---- Phase 2: in-place suffix sum: histo[i] = #elems in buckets >= i ----
  for (int d = 1; d < NB; d <<= 1) {
    const int i0 = tid, i1 = tid + NMS_T;
    const unsigned a0 = (i0 + d < NB) ? histo[i0 + d] : 0u;
    const unsigned a1 = (i1 + d < NB) ? histo[i1 + d] : 0u;
    __syncthreads();
    histo[i0] += a0; histo[i1] += a1;
    __syncthreads();
  }

  // ---- Selection rounds (expected: exactly one) ----
  int btPrev = NB;         // exclusive upper bucket bound of unprocessed region
  unsigned processed = 0;  // suffix count already consumed (buckets >= btPrev)

  // picked-box state, distributed across wave 0's lanes (5 static slots)
  float4 pb0, pb1, pb2, pb3, pb4;
  float  pa0 = 0, pa1 = 0, pa2 = 0, pa3 = 0, pa4 = 0;
  pb0 = pb1 = pb2 = pb3 = pb4 = make_float4(0, 0, 0, 0);
  int np = 0;      // live only in wave 0
  int npAll = 0;   // block-uniform copy

  while (true) {
    // find Bt = largest bucket b < btPrev with remaining-count >= KSEL
    if (tid == 0) sh_bt = 0;
    __syncthreads();
    for (int i = tid; i < NB; i += NMS_T) {
      if (i < btPrev) {
        const unsigned rem  = histo[i] - processed;
        const unsigned remN = (i + 1 < btPrev) ? (histo[i + 1] - processed) : 0u;
        if (rem >= KSEL && remN < KSEL) sh_bt = i;  // unique i satisfies this
      }
    }
    if (tid == 0) sh_cnt = 0;
    __syncthreads();
    const int bt = sh_bt;

    // ---- compact keys with bucket in [bt, btPrev) ----
#pragma unroll
    for (int k = 0; k < ELEMS; ++k) {
      const float v = sc[k];
      if (v > 0.0f) {
        const int bk = (int)(__float_as_uint(v) >> 16) - BUCKET_BASE;
        if (bk >= bt && bk < btPrev) {
          const int pos = atomicAdd(&sh_cnt, 1);
          if (pos < SORTN) {
            const int j = tid + (k << 9);
            keys[pos] = ((unsigned long long)__float_as_uint(v) << 16)
                      | (unsigned long long)(0xFFFFu - (unsigned)j);
          }
        }
      }
    }
    __syncthreads();
    const int cnt = sh_cnt < SORTN ? sh_cnt : SORTN;
    if (cnt == 0) {
      if (bt == 0) break;
      processed = histo[bt]; btPrev = bt;
      continue;
    }
    for (int i = cnt + tid; i < SORTN; i += NMS_T) keys[i] = 0ull;
    __syncthreads();

    // ---- bitonic sort, descending (zeros sink to the end) ----
    for (int kk = 2; kk <= SORTN; kk <<= 1) {
      for (int jj = kk >> 1; jj > 0; jj >>= 1) {
        for (int i = tid; i < SORTN; i += NMS_T) {
          const int l = i ^ jj;
          if (l > i) {
            const unsigned long long a = keys[i], bv = keys[l];
            const bool up = ((i & kk) == 0);
            if (up ? (a < bv) : (a > bv)) { keys[i] = bv; keys[l] = a; }
          }
        }
        __syncthreads();
      }
    }

    // ---- greedy scan over sorted candidates: wave 0 only ----
    if (tid < 64) {
      const int lane = tid;
      int i = 0;
      float4 cb;
      if (cnt > 0) {
        const int idx0 = 0xFFFF - (int)(keys[0] & 0xFFFFull);
        cb = boxesB[idx0];
      }
      while (i < cnt && np < MAXDET) {
        const unsigned long long key = keys[i];
        float4 nxt = cb;
        if (i + 1 < cnt) {
          const int nidx = 0xFFFF - (int)(keys[i + 1] & 0xFFFFull);
          nxt = boxesB[nidx];  // prefetch next candidate's box
        }
        const float ca = box_area(cb);
        bool sup = false;
        if (lane       < np) sup  = iou_gt_half(cb, ca, pb0, pa0);
        if (lane +  64 < np) sup |= iou_gt_half(cb, ca, pb1, pa1);
        if (lane + 128 < np) sup |= iou_gt_half(cb, ca, pb2, pa2);
        if (lane + 192 < np) sup |= iou_gt_half(cb, ca, pb3, pa3);
        if (lane + 256 < np) sup |= iou_gt_half(cb, ca, pb4, pa4);
        if (!__any(sup)) {
          const int slot = np >> 6, owner = np & 63;
          if (lane == owner) {
            if      (slot == 0) { pb0 = cb; pa0 = ca; }
            else if (slot == 1) { pb1 = cb; pa1 = ca; }
            else if (slot == 2) { pb2 = cb; pa2 = ca; }
            else if (slot == 3) { pb3 = cb; pa3 = ca; }
            else                { pb4 = cb; pa4 = ca; }
          }
          if (lane == 0) {
            const unsigned sbits = (unsigned)(key >> 16);
            const int idx        = 0xFFFF - (int)(key & 0xFFFFull);
            // merge key: descending score, tie -> ascending flat position
            const unsigned long long pk =
                ((unsigned long long)sbits << 32) |
                (unsigned long long)(0xFFFFFFFFu - (unsigned)(c * MAXDET + np));
            picks[(size_t)bc * MAXDET + np] =
                make_uint4((unsigned)(pk & 0xFFFFFFFFull), (unsigned)(pk >> 32),
                           (unsigned)idx, 0u);
          }
          ++np;
        }
        cb = nxt;
        ++i;
      }
      if (lane == 0) sh_np = np;
    }
    __syncthreads();
    npAll = sh_np;
    if (npAll >= MAXDET || bt == 0) break;
    processed = histo[bt]; btPrev = bt;
  }

  // invalid tail: key-0 sentinel
  for (int r = npAll + tid; r < MAXDET; r += NMS_T) {
    picks[(size_t)bc * MAXDET + r] = make_uint4(0u, 0u, 0u, 0u);
  }
}

// One wave per image: exact 80-way merge of the per-class descending pick
// lists (= jax.lax.top_k over 24000 candidates, stable tie-break via key).
__global__ __launch_bounds__(64)
void topk_merge_kernel(const uint4* __restrict__ picks,
                       const float* __restrict__ boxes,
                       float* __restrict__ out, int B)
{
  const int b    = blockIdx.x;
  const int lane = threadIdx.x;

  const int clsa = lane;        // classes 0..63
  const int clsb = 64 + lane;   // classes 64..79 on lanes 0..15

  unsigned long long k0a = 0, k1a = 0, k0b = 0, k1b = 0;
  unsigned a0a = 0, a1a = 0, a0b = 0, a1b = 0;
  int ma = 2, mb = 2;

  {
    const uint4* base = picks + (size_t)(b * N_CLS + clsa) * MAXDET;
    const uint4 e0 = base[0], e1 = base[1];
    k0a = ((unsigned long long)e0.y << 32) | e0.x; a0a = e0.z;
    k1a = ((unsigned long long)e1.y << 32) | e1.x; a1a = e1.z;
  }
  if (clsb < N_CLS) {
    const uint4* base = picks + (size_t)(b * N_CLS + clsb) * MAXDET;
    const uint4 e0 = base[0], e1 = base[1];
    k0b = ((unsigned long long)e0.y << 32) | e0.x; a0b = e0.z;
    k1b = ((unsigned long long)e1.y << 32) | e1.x; a1b = e1.z;
  }

  float* outBoxes  = out;                               // [B,300,4]
  float* outScores = out + (size_t)B * MAXDET * 4;      // [B,300]
  float* outLabels = out + (size_t)B * MAXDET * 5;      // [B,300] (as float)

  for (int r = 0; r < MAXDET; ++r) {
    unsigned long long myk = k0a; int mycls = clsa; unsigned mya = a0a;
    if (k0b > myk) { myk = k0b; mycls = clsb; mya = a0b; }
#pragma unroll
    for (int off = 32; off > 0; off >>= 1) {
      const unsigned long long ok = __shfl_xor(myk, off);
      const int      ocls = __shfl_xor(mycls, off);
      const unsigned oa   = __shfl_xor(mya, off);
      if (ok > myk) { myk = ok; mycls = ocls; mya = oa; }
    }
    // all lanes now hold the winner (keys unique except the 0 sentinel)

    if (lane == 0) {
      const size_t o = (size_t)b * MAXDET + r;
      if (myk == 0ull) {
        reinterpret_cast<float4*>(outBoxes)[o] = make_float4(-1.f, -1.f, -1.f, -1.f);
        outScores[o] = -1.f;
        outLabels[o] = -1.f;
      } else {
        const float4 bb =
            reinterpret_cast<const float4*>(boxes)[(size_t)b * N_ANCH + mya];
        reinterpret_cast<float4*>(outBoxes)[o] = bb;
        outScores[o] = __uint_as_float((unsigned)(myk >> 32));
        outLabels[o] = (float)mycls;
      }
    }

    if (myk != 0ull) {  // advance winning class's head (owner lane only)
      const int owner = mycls & 63;
      if (lane == owner) {
        if (mycls < 64) {
          k0a = k1a; a0a = a1a;
          if (ma < MAXDET) {
            const uint4 e = picks[(size_t)(b * N_CLS + mycls) * MAXDET + ma];
            k1a = ((unsigned long long)e.y << 32) | e.x; a1a = e.z; ++ma;
          } else k1a = 0ull;
        } else {
          k0b = k1b; a0b = a1b;
          if (mb < MAXDET) {
            const uint4 e = picks[(size_t)(b * N_CLS + mycls) * MAXDET + mb];
            k1b = ((unsigned long long)e.y << 32) | e.x; a1b = e.z; ++mb;
          } else k1b = 0ull;
        }
      }
    }
  }
}

extern "C" void kernel_launch(void* const* d_in, const int* in_sizes, int n_in,
                              void* d_out, int out_size, void* d_ws, size_t ws_size,
                              hipStream_t stream)
{
  const float* boxes = (const float*)d_in[0];
  const float* cls   = (const float*)d_in[1];
  const int B = in_sizes[0] / (N_ANCH * 4);  // = 2

  // workspace: picks[B*C][300] as uint4 {key_lo, key_hi, anchor, pad} = 768 KB
  uint4* picks = (uint4*)d_ws;

  nms_kernel<<<dim3(B * N_CLS), dim3(NMS_T), 0, stream>>>(boxes, cls, picks);
  topk_merge_kernel<<<dim3(B), dim3(64), 0, stream>>>(picks, boxes, (float*)d_out, B);
}

// Round 3
// 338.592 us; speedup vs baseline: 9.6116x; 1.9559x over previous
//
#include <hip/hip_runtime.h>
#include <cstdint>
#include <cstddef>

#define N_ANCH 20000
#define N_CLS  80
#define MAXDET 300
#define NMS_T  512
#define ELEMS  40      // ceil(N_ANCH / NMS_T)
#define SORTN  1024    // NMS bitonic sort size (pow2)
#define KSEL   768     // target top-K per selection round
#define NB     1024    // coarse histogram buckets (564 used; pow2)
#define MSORT  1024    // merge sort size
#define BUCKET_BASE 0x3D4C  // float bits of ~0.05 >> 16

__device__ __forceinline__ float box_area(float4 b) {
  return __fmul_rn(__fsub_rn(b.z, b.x), __fsub_rn(b.w, b.y));
}

// IOU, unfused IEEE ops, exactly the reference's association order.
// a = candidate (per-element area first in denom), b = selected/picked.
__device__ __forceinline__ bool iou_gt_half(float4 a, float aa, float4 b, float ab) {
  const float xx1 = fmaxf(a.x, b.x);
  const float yy1 = fmaxf(a.y, b.y);
  const float xx2 = fminf(a.z, b.z);
  const float yy2 = fminf(a.w, b.w);
  const float iw  = fmaxf(__fsub_rn(xx2, xx1), 0.0f);
  const float ih  = fmaxf(__fsub_rn(yy2, yy1), 0.0f);
  const float inter = __fmul_rn(iw, ih);
  const float denom = __fsub_rn(__fadd_rn(aa, ab), inter);
  return __fdiv_rn(inter, denom) > 0.5f;
}

// One block per (image, class). Sorted-candidate greedy NMS (exact):
// candidate suppressed iff IOU>0.5 with an already-picked box.
__global__ __launch_bounds__(NMS_T)
void nms_kernel(const float* __restrict__ boxes,
                const float* __restrict__ cls,
                uint4* __restrict__ picks)
{
  const int bc  = blockIdx.x;
  const int b   = bc / N_CLS;
  const int c   = bc - b * N_CLS;
  const int tid = threadIdx.x;

  const float4* boxesB = reinterpret_cast<const float4*>(boxes) + (size_t)b * N_ANCH;
  const float*  clsB   = cls + ((size_t)b * N_ANCH) * N_CLS + c;

  __shared__ unsigned long long keys[SORTN];   // 8 KB
  __shared__ unsigned histo[NB];               // 4 KB (becomes suffix-sum)
  __shared__ float4 pBox[MAXDET];              // picked boxes (broadcast reads)
  __shared__ float  pArea[MAXDET];
  __shared__ int sh_cnt, sh_np, sh_bt;

  for (int i = tid; i < NB; i += NMS_T) histo[i] = 0;
  if (tid == 0) sh_np = 0;
  __syncthreads();

  // ---- Phase 1: read scores (cached in regs), build histogram ----
  float sc[ELEMS];
#pragma unroll
  for (int k = 0; k < ELEMS; ++k) {
    const int j = tid + (k << 9);
    float v = -1.0f;
    if (j < N_ANCH) {
      const float t = clsB[(size_t)j * N_CLS];
      if (t > 0.05f) v = t;
    }
    sc[k] = v;
    if (v > 0.0f) {
      int bk = (int)(__float_as_uint(v) >> 16) - BUCKET_BASE;
      if (bk > NB - 1) bk = NB - 1;
      atomicAdd(&histo[bk], 1u);
    }
  }
  __syncthreads();

  // ---- Phase 2: suffix sum: histo[i] = #elems in buckets >= i ----
  for (int d = 1; d < NB; d <<= 1) {
    const int i0 = tid, i1 = tid + NMS_T;
    const unsigned a0 = (i0 + d < NB) ? histo[i0 + d] : 0u;
    const unsigned a1 = (i1 + d < NB) ? histo[i1 + d] : 0u;
    __syncthreads();
    histo[i0] += a0; histo[i1] += a1;
    __syncthreads();
  }

  // ---- Selection rounds (expected: exactly one) ----
  int btPrev = NB;
  unsigned processed = 0;

  while (true) {
    if (tid == 0) { sh_bt = 0; sh_cnt = 0; }
    __syncthreads();
    // largest bucket bt < btPrev with remaining >= KSEL (unique)
    for (int i = tid; i < NB; i += NMS_T) {
      if (i < btPrev) {
        const unsigned rem  = histo[i] - processed;
        const unsigned remN = (i + 1 < btPrev) ? (histo[i + 1] - processed) : 0u;
        if (rem >= KSEL && remN < KSEL) sh_bt = i;
      }
    }
    __syncthreads();
    const int bt = sh_bt;

    // compact keys with bucket in [lo, btPrev)
    int lo = bt;
#pragma unroll
    for (int k = 0; k < ELEMS; ++k) {
      const float v = sc[k];
      if (v > 0.0f) {
        int bk = (int)(__float_as_uint(v) >> 16) - BUCKET_BASE;
        if (bk > NB - 1) bk = NB - 1;
        if (bk >= lo && bk < btPrev) {
          const int pos = atomicAdd(&sh_cnt, 1);
          if (pos < SORTN) {
            const int j = tid + (k << 9);
            keys[pos] = ((unsigned long long)__float_as_uint(v) << 16)
                      | (unsigned long long)(0xFFFFu - (unsigned)j);
          }
        }
      }
    }
    __syncthreads();
    int btEff = bt;
    if (sh_cnt > SORTN && bt + 1 < btPrev) {
      // overflow: exclude boundary bucket (remaining there < KSEL <= SORTN)
      if (tid == 0) sh_cnt = 0;
      __syncthreads();
      lo = bt + 1;
#pragma unroll
      for (int k = 0; k < ELEMS; ++k) {
        const float v = sc[k];
        if (v > 0.0f) {
          int bk = (int)(__float_as_uint(v) >> 16) - BUCKET_BASE;
          if (bk > NB - 1) bk = NB - 1;
          if (bk >= lo && bk < btPrev) {
            const int pos = atomicAdd(&sh_cnt, 1);
            if (pos < SORTN) {
              const int j = tid + (k << 9);
              keys[pos] = ((unsigned long long)__float_as_uint(v) << 16)
                        | (unsigned long long)(0xFFFFu - (unsigned)j);
            }
          }
        }
      }
      __syncthreads();
      btEff = bt + 1;
    }
    const int cnt = sh_cnt < SORTN ? sh_cnt : SORTN;

    if (cnt == 0) {
      if (btEff == 0) break;
      processed = histo[btEff]; btPrev = btEff;
      continue;
    }
    for (int i = cnt + tid; i < SORTN; i += NMS_T) keys[i] = 0ull;
    __syncthreads();

    // ---- bitonic sort 1024, descending (zeros sink) ----
    for (int kk = 2; kk <= SORTN; kk <<= 1) {
      for (int jj = kk >> 1; jj > 0; jj >>= 1) {
        for (int i = tid; i < SORTN; i += NMS_T) {
          const int l = i ^ jj;
          if (l > i) {
            const unsigned long long a = keys[i], bv = keys[l];
            const bool up = ((i & kk) == 0);
            if (up ? (a < bv) : (a > bv)) { keys[i] = bv; keys[l] = a; }
          }
        }
        __syncthreads();
      }
    }

    // ---- batch-64 wave-parallel greedy scan (wave 0) ----
    if (tid < 64) {
      const int lane = tid;
      int np = sh_np;
      for (int i0 = 0; i0 < cnt && np < MAXDET; i0 += 64) {
        const int ci = i0 + lane;
        const bool haveC = ci < cnt;
        unsigned long long key = 0ull;
        if (haveC) key = keys[ci];
        const int idx = 0xFFFF - (int)(key & 0xFFFFull);
        float4 cb = make_float4(0.f, 0.f, 0.f, 0.f);
        if (haveC) cb = boxesB[idx];
        const float ca = box_area(cb);
        bool alive = haveC;
        for (int j = 0; j < np; ++j) {
          if (alive && iou_gt_half(cb, ca, pBox[j], pArea[j])) alive = false;
        }
        unsigned long long remM = __ballot(alive);
        while (remM != 0ull && np < MAXDET) {
          const int s = __ffsll(remM) - 1;
          const float bx = __shfl(cb.x, s), by = __shfl(cb.y, s);
          const float bz = __shfl(cb.z, s), bw = __shfl(cb.w, s);
          const float ba = __shfl(ca, s);
          if (lane == s) {
            const unsigned sbits = (unsigned)(key >> 16);
            const unsigned long long pk =
                ((unsigned long long)sbits << 32) |
                (unsigned long long)(0xFFFFFFFFu - (unsigned)(c * MAXDET + np));
            picks[(size_t)bc * MAXDET + np] =
                make_uint4((unsigned)(pk & 0xFFFFFFFFull), (unsigned)(pk >> 32),
                           (unsigned)idx, 0u);
            alive = false;
          }
          if (lane == 0) { pBox[np] = make_float4(bx, by, bz, bw); pArea[np] = ba; }
          if (alive && lane > s) {
            if (iou_gt_half(cb, ca, make_float4(bx, by, bz, bw), ba)) alive = false;
          }
          ++np;
          remM = __ballot(alive);
        }
      }
      if (lane == 0) sh_np = np;
    }
    __syncthreads();
    if (sh_np >= MAXDET || btEff == 0) break;
    processed = histo[btEff]; btPrev = btEff;
  }
  __syncthreads();

  const int npF = sh_np;
  for (int r = npF + tid; r < MAXDET; r += NMS_T) {
    picks[(size_t)bc * MAXDET + r] = make_uint4(0u, 0u, 0u, 0u);
  }
}

// One block per image: exact top-300 of the 24000 pick keys via two-level
// histogram select + 1024 bitonic sort (stable tie-break lives in the key).
__global__ __launch_bounds__(512)
void topk_merge_kernel(const uint4* __restrict__ picks,
                       const float* __restrict__ boxes,
                       float* __restrict__ out, int B)
{
  const int b   = blockIdx.x;
  const int tid = threadIdx.x;
  const uint4* pk = picks + (size_t)b * N_CLS * MAXDET;
  const int TOT = N_CLS * MAXDET;

  __shared__ unsigned long long mk[MSORT];   // 8 KB
  __shared__ unsigned ma_[MSORT];            // 4 KB (anchors)
  __shared__ unsigned histo[NB];             // 4 KB
  __shared__ unsigned histo2[256];           // 1 KB
  __shared__ int sh_cnt, sh_b1, sh_b2;

  for (int i = tid; i < NB; i += 512) histo[i] = 0;
  if (tid < 256) histo2[tid] = 0;
  if (tid == 0) { sh_cnt = 0; sh_b1 = -1; sh_b2 = 0; }
  __syncthreads();

  // coarse histogram on score bits [31:16]
  for (int i = tid; i < TOT; i += 512) {
    const uint4 e = pk[i];
    const unsigned long long key = ((unsigned long long)e.y << 32) | e.x;
    if (key != 0ull) {
      int bk = (int)(key >> 48) - BUCKET_BASE;
      if (bk > NB - 1) bk = NB - 1;
      if (bk < 0) bk = 0;
      atomicAdd(&histo[bk], 1u);
    }
  }
  __syncthreads();
  // suffix sum (1024 entries, 512 threads)
  for (int d = 1; d < NB; d <<= 1) {
    const int i0 = tid, i1 = tid + 512;
    const unsigned a0 = (i0 + d < NB) ? histo[i0 + d] : 0u;
    const unsigned a1 = (i1 + d < NB) ? histo[i1 + d] : 0u;
    __syncthreads();
    histo[i0] += a0; histo[i1] += a1;
    __syncthreads();
  }
  const unsigned total = histo[0];

  int b1 = -1, b2 = 0;
  if (total > MAXDET) {  // block-uniform branch
    for (int i = tid; i < NB; i += 512) {
      const unsigned rem  = histo[i];
      const unsigned remN = (i + 1 < NB) ? histo[i + 1] : 0u;
      if (rem >= MAXDET && remN < MAXDET) sh_b1 = i;
    }
    __syncthreads();
    b1 = sh_b1;
    const unsigned above = (b1 + 1 < NB) ? histo[b1 + 1] : 0u;  // < 300
    const unsigned need2 = MAXDET - above;                       // >= 1
    // fine histogram (score bits [15:8]) within boundary bucket b1
    for (int i = tid; i < TOT; i += 512) {
      const uint4 e = pk[i];
      const unsigned long long key = ((unsigned long long)e.y << 32) | e.x;
      if (key != 0ull) {
        int bk = (int)(key >> 48) - BUCKET_BASE;
        if (bk > NB - 1) bk = NB - 1;
        if (bk < 0) bk = 0;
        if (bk == b1) atomicAdd(&histo2[(unsigned)(key >> 40) & 0xFFu], 1u);
      }
    }
    __syncthreads();
    for (int d = 1; d < 256; d <<= 1) {
      unsigned a0 = 0;
      if (tid < 256) a0 = (tid + d < 256) ? histo2[tid + d] : 0u;
      __syncthreads();
      if (tid < 256) histo2[tid] += a0;
      __syncthreads();
    }
    for (int i = tid; i < 256; i += 512) {
      const unsigned rem  = histo2[i];
      const unsigned remN = (i + 1 < 256) ? histo2[i + 1] : 0u;
      if (rem >= need2 && remN < need2) sh_b2 = i;
    }
    __syncthreads();
    b2 = sh_b2;
  }

  // compact qualifying keys (b1 == -1 -> take all valid)
  for (int i = tid; i < MSORT; i += 512) mk[i] = 0ull;
  __syncthreads();
  for (int i = tid; i < TOT; i += 512) {
    const uint4 e = pk[i];
    const unsigned long long key = ((unsigned long long)e.y << 32) | e.x;
    if (key != 0ull) {
      int k1 = (int)(key >> 48) - BUCKET_BASE;
      if (k1 > NB - 1) k1 = NB - 1;
      if (k1 < 0) k1 = 0;
      const int k2 = (int)((key >> 40) & 0xFFull);
      if (k1 > b1 || (k1 == b1 && k2 >= b2)) {
        const int pos = atomicAdd(&sh_cnt, 1);
        if (pos < MSORT) { mk[pos] = key; ma_[pos] = e.z; }
      }
    }
  }
  __syncthreads();

  // bitonic sort 1024 desc, carrying anchors
  for (int kk = 2; kk <= MSORT; kk <<= 1) {
    for (int jj = kk >> 1; jj > 0; jj >>= 1) {
      for (int i = tid; i < MSORT; i += 512) {
        const int l = i ^ jj;
        if (l > i) {
          const unsigned long long a = mk[i], bv = mk[l];
          const bool up = ((i & kk) == 0);
          if (up ? (a < bv) : (a > bv)) {
            mk[i] = bv; mk[l] = a;
            const unsigned t = ma_[i]; ma_[i] = ma_[l]; ma_[l] = t;
          }
        }
      }
      __syncthreads();
    }
  }

  float* outBoxes  = out;                            // [B,300,4]
  float* outScores = out + (size_t)B * MAXDET * 4;   // [B,300]
  float* outLabels = out + (size_t)B * MAXDET * 5;   // [B,300] (as float)
  for (int r = tid; r < MAXDET; r += 512) {
    const unsigned long long key = mk[r];
    const size_t o = (size_t)b * MAXDET + r;
    if (key == 0ull) {
      reinterpret_cast<float4*>(outBoxes)[o] = make_float4(-1.f, -1.f, -1.f, -1.f);
      outScores[o] = -1.f;
      outLabels[o] = -1.f;
    } else {
      const unsigned posFlat = 0xFFFFFFFFu - (unsigned)(key & 0xFFFFFFFFull);
      const int ccls = (int)(posFlat / MAXDET);
      reinterpret_cast<float4*>(outBoxes)[o] =
          reinterpret_cast<const float4*>(boxes)[(size_t)b * N_ANCH + ma_[r]];
      outScores[o] = __uint_as_float((unsigned)(key >> 32));
      outLabels[o] = (float)ccls;
    }
  }
}

extern "C" void kernel_launch(void* const* d_in, const int* in_sizes, int n_in,
                              void* d_out, int out_size, void* d_ws, size_t ws_size,
                              hipStream_t stream)
{
  const float* boxes = (const float*)d_in[0];
  const float* cls   = (const float*)d_in[1];
  const int B = in_sizes[0] / (N_ANCH * 4);  // = 2

  // workspace: picks[B*C][300] as uint4 {key_lo, key_hi, anchor, pad} = 768 KB
  uint4* picks = (uint4*)d_ws;

  nms_kernel<<<dim3(B * N_CLS), dim3(NMS_T), 0, stream>>>(boxes, cls, picks);
  topk_merge_kernel<<<dim3(B), dim3(512), 0, stream>>>(picks, boxes, (float*)d_out, B);
}

// Round 6
// 324.331 us; speedup vs baseline: 10.0343x; 1.0440x over previous
//
#include <hip/hip_runtime.h>
#include <cstdint>
#include <cstddef>

#define N_ANCH 20000
#define N_CLS  80
#define MAXDET 300
#define NMS_T  512
#define ELEMS  40      // scores per thread (40 = 10 float4)
#define SORTN  1024    // NMS bitonic sort size (pow2)
#define KSEL   768     // target top-K per selection round
#define NB     1024    // coarse histogram buckets (564 used; pow2)
#define MSORT  1024    // merge sort size
#define BUCKET_BASE 0x3D4C  // float bits of ~0.05 >> 16

#define TP_T   320     // transpose threads
#define TILE_A 160     // anchors per transpose tile (20000 = 125 * 160)

__device__ __forceinline__ float box_area(float4 b) {
  return __fmul_rn(__fsub_rn(b.z, b.x), __fsub_rn(b.w, b.y));
}

// IOU, unfused IEEE ops, exactly the reference's association order.
__device__ __forceinline__ bool iou_gt_half(float4 a, float aa, float4 b, float ab) {
  const float xx1 = fmaxf(a.x, b.x);
  const float yy1 = fmaxf(a.y, b.y);
  const float xx2 = fminf(a.z, b.z);
  const float yy2 = fminf(a.w, b.w);
  const float iw  = fmaxf(__fsub_rn(xx2, xx1), 0.0f);
  const float ih  = fmaxf(__fsub_rn(yy2, yy1), 0.0f);
  const float inter = __fmul_rn(iw, ih);
  const float denom = __fsub_rn(__fadd_rn(aa, ab), inter);
  return __fdiv_rn(inter, denom) > 0.5f;
}

// cls [B, N, 80] -> clsT [B, 80, N]; tile = 160 anchors x 80 classes.
// LDS layout [class][anchor/4] (float4, stride 41) -> b128 reads on write side.
__global__ __launch_bounds__(TP_T)
void transpose_kernel(const float* __restrict__ cls, float* __restrict__ clsT)
{
  const int blk  = blockIdx.x;           // b * 125 + tile
  const int b    = blk / 125;
  const int tile = blk - b * 125;
  const int n0   = tile * TILE_A;
  const int t    = threadIdx.x;

  __shared__ float4 lds[N_CLS * 41];     // 52.5 KB

  const float4* in4 =
      reinterpret_cast<const float4*>(cls + ((size_t)b * N_ANCH + n0) * N_CLS);
  float* ldsF = reinterpret_cast<float*>(lds);

#pragma unroll
  for (int i = 0; i < 10; ++i) {
    const int f4 = t + i * TP_T;         // < 3200
    const float4 v = in4[f4];
    const int a  = f4 / 20;              // anchor within tile (20 float4 per anchor)
    const int c0 = (f4 - a * 20) * 4;    // class of v.x
    ldsF[(c0 + 0) * 164 + a] = v.x;
    ldsF[(c0 + 1) * 164 + a] = v.y;
    ldsF[(c0 + 2) * 164 + a] = v.z;
    ldsF[(c0 + 3) * 164 + a] = v.w;
  }
  __syncthreads();

  float4* out4 = reinterpret_cast<float4*>(clsT + (size_t)b * N_CLS * N_ANCH);
#pragma unroll
  for (int i = 0; i < 10; ++i) {
    const int f4 = t + i * TP_T;         // < 3200
    const int c  = f4 / 40;              // 40 float4 per class row
    const int a4 = f4 - c * 40;
    out4[(size_t)c * (N_ANCH / 4) + (n0 / 4) + a4] = lds[c * 41 + a4];
  }
}

// One block per (image, class). Sorted-candidate greedy NMS (exact):
// candidate suppressed iff IOU>0.5 with an already-picked box.
__global__ __launch_bounds__(NMS_T)
void nms_kernel(const float* __restrict__ boxes,
                const float* __restrict__ cls,
                const float* __restrict__ clsT,
                uint4* __restrict__ picks, int useT)
{
  const int bc  = blockIdx.x;
  const int b   = bc / N_CLS;
  const int c   = bc - b * N_CLS;
  const int tid = threadIdx.x;

  const float4* boxesB = reinterpret_cast<const float4*>(boxes) + (size_t)b * N_ANCH;

  __shared__ unsigned long long keys[SORTN];   // 8 KB
  __shared__ unsigned histo[NB];               // 4 KB (becomes suffix-sum)
  __shared__ float4 pBox[MAXDET];
  __shared__ float  pArea[MAXDET];
  __shared__ int sh_cnt, sh_np, sh_bt;

  for (int i = tid; i < NB; i += NMS_T) histo[i] = 0;
  if (tid == 0) sh_np = 0;
  __syncthreads();

  // ---- Phase 1: read scores (regs), build histogram ----
  // element j for reg (k,m): j = ((tid + ((k>>2)<<9)) << 2) + (k&3)
  float sc[ELEMS];
  if (useT) {
    const float4* cT4 =
        reinterpret_cast<const float4*>(clsT + (size_t)bc * N_ANCH);
#pragma unroll
    for (int k = 0; k < 10; ++k) {
      const int f4 = tid + (k << 9);
      float4 v = make_float4(-1.f, -1.f, -1.f, -1.f);
      if (f4 < N_ANCH / 4) v = cT4[f4];
#pragma unroll
      for (int m = 0; m < 4; ++m) {
        const float t = (&v.x)[m];
        const float val = (t > 0.05f) ? t : -1.0f;
        sc[k * 4 + m] = val;
        if (val > 0.0f) {
          int bk = (int)(__float_as_uint(val) >> 16) - BUCKET_BASE;
          if (bk > NB - 1) bk = NB - 1;
          atomicAdd(&histo[bk], 1u);
        }
      }
    }
  } else {
    const float* clsB = cls + ((size_t)b * N_ANCH) * N_CLS + c;
#pragma unroll
    for (int k = 0; k < 10; ++k) {
      const int f4 = tid + (k << 9);
#pragma unroll
      for (int m = 0; m < 4; ++m) {
        const int j = (f4 << 2) + m;
        float val = -1.0f;
        if (j < N_ANCH) {
          const float t = clsB[(size_t)j * N_CLS];
          if (t > 0.05f) val = t;
        }
        sc[k * 4 + m] = val;
        if (val > 0.0f) {
          int bk = (int)(__float_as_uint(val) >> 16) - BUCKET_BASE;
          if (bk > NB - 1) bk = NB - 1;
          atomicAdd(&histo[bk], 1u);
        }
      }
    }
  }
  __syncthreads();

  // ---- Phase 2: suffix sum: histo[i] = #elems in buckets >= i ----
  for (int d = 1; d < NB; d <<= 1) {
    const int i0 = tid, i1 = tid + NMS_T;
    const unsigned a0 = (i0 + d < NB) ? histo[i0 + d] : 0u;
    const unsigned a1 = (i1 + d < NB) ? histo[i1 + d] : 0u;
    __syncthreads();
    histo[i0] += a0; histo[i1] += a1;
    __syncthreads();
  }

  // ---- Selection rounds (expected: exactly one) ----
  int btPrev = NB;
  unsigned processed = 0;

  while (true) {
    if (tid == 0) { sh_bt = 0; sh_cnt = 0; }
    __syncthreads();
    for (int i = tid; i < NB; i += NMS_T) {
      if (i < btPrev) {
        const unsigned rem  = histo[i] - processed;
        const unsigned remN = (i + 1 < btPrev) ? (histo[i + 1] - processed) : 0u;
        if (rem >= KSEL && remN < KSEL) sh_bt = i;
      }
    }
    __syncthreads();
    const int bt = sh_bt;

    // compact keys with bucket in [lo, btPrev)
    int lo = bt;
#pragma unroll
    for (int k = 0; k < ELEMS; ++k) {
      const float v = sc[k];
      if (v > 0.0f) {
        int bk = (int)(__float_as_uint(v) >> 16) - BUCKET_BASE;
        if (bk > NB - 1) bk = NB - 1;
        if (bk >= lo && bk < btPrev) {
          const int pos = atomicAdd(&sh_cnt, 1);
          if (pos < SORTN) {
            const int j = ((tid + ((k >> 2) << 9)) << 2) + (k & 3);
            keys[pos] = ((unsigned long long)__float_as_uint(v) << 16)
                      | (unsigned long long)(0xFFFFu - (unsigned)j);
          }
        }
      }
    }
    __syncthreads();
    int btEff = bt;
    if (sh_cnt > SORTN && bt + 1 < btPrev) {
      if (tid == 0) sh_cnt = 0;
      __syncthreads();
      lo = bt + 1;
#pragma unroll
      for (int k = 0; k < ELEMS; ++k) {
        const float v = sc[k];
        if (v > 0.0f) {
          int bk = (int)(__float_as_uint(v) >> 16) - BUCKET_BASE;
          if (bk > NB - 1) bk = NB - 1;
          if (bk >= lo && bk < btPrev) {
            const int pos = atomicAdd(&sh_cnt, 1);
            if (pos < SORTN) {
              const int j = ((tid + ((k >> 2) << 9)) << 2) + (k & 3);
              keys[pos] = ((unsigned long long)__float_as_uint(v) << 16)
                        | (unsigned long long)(0xFFFFu - (unsigned)j);
            }
          }
        }
      }
      __syncthreads();
      btEff = bt + 1;
    }
    const int cnt = sh_cnt < SORTN ? sh_cnt : SORTN;

    if (cnt == 0) {
      if (btEff == 0) break;
      processed = histo[btEff]; btPrev = btEff;
      continue;
    }
    for (int i = cnt + tid; i < SORTN; i += NMS_T) keys[i] = 0ull;
    __syncthreads();

    // ---- bitonic sort 1024, descending (zeros sink) ----
    for (int kk = 2; kk <= SORTN; kk <<= 1) {
      for (int jj = kk >> 1; jj > 0; jj >>= 1) {
        for (int i = tid; i < SORTN; i += NMS_T) {
          const int l = i ^ jj;
          if (l > i) {
            const unsigned long long a = keys[i], bv = keys[l];
            const bool up = ((i & kk) == 0);
            if (up ? (a < bv) : (a > bv)) { keys[i] = bv; keys[l] = a; }
          }
        }
        __syncthreads();
      }
    }

    // ---- batch-64 wave-parallel greedy scan (wave 0) ----
    if (tid < 64) {
      const int lane = tid;
      int np = sh_np;
      for (int i0 = 0; i0 < cnt && np < MAXDET; i0 += 64) {
        const int ci = i0 + lane;
        const bool haveC = ci < cnt;
        unsigned long long key = 0ull;
        if (haveC) key = keys[ci];
        const int idx = 0xFFFF - (int)(key & 0xFFFFull);
        float4 cb = make_float4(0.f, 0.f, 0.f, 0.f);
        if (haveC) cb = boxesB[idx];
        const float ca = box_area(cb);
        bool alive = haveC;
        for (int j = 0; j < np; ++j) {
          if (alive && iou_gt_half(cb, ca, pBox[j], pArea[j])) alive = false;
        }
        unsigned long long remM = __ballot(alive);
        while (remM != 0ull && np < MAXDET) {
          const int s = __ffsll(remM) - 1;
          const float bx = __shfl(cb.x, s), by = __shfl(cb.y, s);
          const float bz = __shfl(cb.z, s), bw = __shfl(cb.w, s);
          const float ba = __shfl(ca, s);
          if (lane == s) {
            const unsigned sbits = (unsigned)(key >> 16);
            const unsigned long long pk =
                ((unsigned long long)sbits << 32) |
                (unsigned long long)(0xFFFFFFFFu - (unsigned)(c * MAXDET + np));
            picks[(size_t)bc * MAXDET + np] =
                make_uint4((unsigned)(pk & 0xFFFFFFFFull), (unsigned)(pk >> 32),
                           (unsigned)idx, 0u);
            alive = false;
          }
          if (lane == 0) { pBox[np] = make_float4(bx, by, bz, bw); pArea[np] = ba; }
          if (alive && lane > s) {
            if (iou_gt_half(cb, ca, make_float4(bx, by, bz, bw), ba)) alive = false;
          }
          ++np;
          remM = __ballot(alive);
        }
      }
      if (lane == 0) sh_np = np;
    }
    __syncthreads();
    if (sh_np >= MAXDET || btEff == 0) break;
    processed = histo[btEff]; btPrev = btEff;
  }
  __syncthreads();

  const int npF = sh_np;
  for (int r = npF + tid; r < MAXDET; r += NMS_T) {
    picks[(size_t)bc * MAXDET + r] = make_uint4(0u, 0u, 0u, 0u);
  }
}

// One block per image: exact top-300 of the 24000 pick keys via two-level
// histogram select + 1024 bitonic sort (stable tie-break lives in the key).
__global__ __launch_bounds__(512)
void topk_merge_kernel(const uint4* __restrict__ picks,
                       const float* __restrict__ boxes,
                       float* __restrict__ out, int B)
{
  const int b   = blockIdx.x;
  const int tid = threadIdx.x;
  const uint4* pk = picks + (size_t)b * N_CLS * MAXDET;
  const int TOT = N_CLS * MAXDET;

  __shared__ unsigned long long mk[MSORT];
  __shared__ unsigned ma_[MSORT];
  __shared__ unsigned histo[NB];
  __shared__ unsigned histo2[256];
  __shared__ int sh_cnt, sh_b1, sh_b2;

  for (int i = tid; i < NB; i += 512) histo[i] = 0;
  if (tid < 256) histo2[tid] = 0;
  if (tid == 0) { sh_cnt = 0; sh_b1 = -1; sh_b2 = 0; }
  __syncthreads();

  for (int i = tid; i < TOT; i += 512) {
    const uint4 e = pk[i];
    const unsigned long long key = ((unsigned long long)e.y << 32) | e.x;
    if (key != 0ull) {
      int bk = (int)(key >> 48) - BUCKET_BASE;
      if (bk > NB - 1) bk = NB - 1;
      if (bk < 0) bk = 0;
      atomicAdd(&histo[bk], 1u);
    }
  }
  __syncthreads();
  for (int d = 1; d < NB; d <<= 1) {
    const int i0 = tid, i1 = tid + 512;
    const unsigned a0 = (i0 + d < NB) ? histo[i0 + d] : 0u;
    const unsigned a1 = (i1 + d < NB) ? histo[i1 + d] : 0u;
    __syncthreads();
    histo[i0] += a0; histo[i1] += a1;
    __syncthreads();
  }
  const unsigned total = histo[0];

  int b1 = -1, b2 = 0;
  if (total > MAXDET) {
    for (int i = tid; i < NB; i += 512) {
      const unsigned rem  = histo[i];
      const unsigned remN = (i + 1 < NB) ? histo[i + 1] : 0u;
      if (rem >= MAXDET && remN < MAXDET) sh_b1 = i;
    }
    __syncthreads();
    b1 = sh_b1;
    const unsigned above = (b1 + 1 < NB) ? histo[b1 + 1] : 0u;
    const unsigned need2 = MAXDET - above;
    for (int i = tid; i < TOT; i += 512) {
      const uint4 e = pk[i];
      const unsigned long long key = ((unsigned long long)e.y << 32) | e.x;
      if (key != 0ull) {
        int bk = (int)(key >> 48) - BUCKET_BASE;
        if (bk > NB - 1) bk = NB - 1;
        if (bk < 0) bk = 0;
        if (bk == b1) atomicAdd(&histo2[(unsigned)(key >> 40) & 0xFFu], 1u);
      }
    }
    __syncthreads();
    for (int d = 1; d < 256; d <<= 1) {
      unsigned a0 = 0;
      if (tid < 256) a0 = (tid + d < 256) ? histo2[tid + d] : 0u;
      __syncthreads();
      if (tid < 256) histo2[tid] += a0;
      __syncthreads();
    }
    for (int i = tid; i < 256; i += 512) {
      const unsigned rem  = histo2[i];
      const unsigned remN = (i + 1 < 256) ? histo2[i + 1] : 0u;
      if (rem >= need2 && remN < need2) sh_b2 = i;
    }
    __syncthreads();
    b2 = sh_b2;
  }

  for (int i = tid; i < MSORT; i += 512) mk[i] = 0ull;
  __syncthreads();
  for (int i = tid; i < TOT; i += 512) {
    const uint4 e = pk[i];
    const unsigned long long key = ((unsigned long long)e.y << 32) | e.x;
    if (key != 0ull) {
      int k1 = (int)(key >> 48) - BUCKET_BASE;
      if (k1 > NB - 1) k1 = NB - 1;
      if (k1 < 0) k1 = 0;
      const int k2 = (int)((key >> 40) & 0xFFull);
      if (k1 > b1 || (k1 == b1 && k2 >= b2)) {
        const int pos = atomicAdd(&sh_cnt, 1);
        if (pos < MSORT) { mk[pos] = key; ma_[pos] = e.z; }
      }
    }
  }
  __syncthreads();

  for (int kk = 2; kk <= MSORT; kk <<= 1) {
    for (int jj = kk >> 1; jj > 0; jj >>= 1) {
      for (int i = tid; i < MSORT; i += 512) {
        const int l = i ^ jj;
        if (l > i) {
          const unsigned long long a = mk[i], bv = mk[l];
          const bool up = ((i & kk) == 0);
          if (up ? (a < bv) : (a > bv)) {
            mk[i] = bv; mk[l] = a;
            const unsigned t = ma_[i]; ma_[i] = ma_[l]; ma_[l] = t;
          }
        }
      }
      __syncthreads();
    }
  }

  float* outBoxes  = out;
  float* outScores = out + (size_t)B * MAXDET * 4;
  float* outLabels = out + (size_t)B * MAXDET * 5;
  for (int r = tid; r < MAXDET; r += 512) {
    const unsigned long long key = mk[r];
    const size_t o = (size_t)b * MAXDET + r;
    if (key == 0ull) {
      reinterpret_cast<float4*>(outBoxes)[o] = make_float4(-1.f, -1.f, -1.f, -1.f);
      outScores[o] = -1.f;
      outLabels[o] = -1.f;
    } else {
      const unsigned posFlat = 0xFFFFFFFFu - (unsigned)(key & 0xFFFFFFFFull);
      const int ccls = (int)(posFlat / MAXDET);
      reinterpret_cast<float4*>(outBoxes)[o] =
          reinterpret_cast<const float4*>(boxes)[(size_t)b * N_ANCH + ma_[r]];
      outScores[o] = __uint_as_float((unsigned)(key >> 32));
      outLabels[o] = (float)ccls;
    }
  }
}

extern "C" void kernel_launch(void* const* d_in, const int* in_sizes, int n_in,
                              void* d_out, int out_size, void* d_ws, size_t ws_size,
                              hipStream_t stream)
{
  const float* boxes = (const float*)d_in[0];
  const float* cls   = (const float*)d_in[1];
  const int B = in_sizes[0] / (N_ANCH * 4);  // = 2

  // ws layout: picks [B*C*300] uint4 (768 KB), then clsT [B,80,N] (12.8 MB)
  const size_t picksBytes = (size_t)B * N_CLS * MAXDET * sizeof(uint4);
  const size_t clsTBytes  = (size_t)B * N_CLS * N_ANCH * sizeof(float);
  uint4* picks = (uint4*)d_ws;
  float* clsT  = (float*)((char*)d_ws + picksBytes);
  const int useT = (ws_size >= picksBytes + clsTBytes) ? 1 : 0;

  if (useT) {
    transpose_kernel<<<dim3(B * (N_ANCH / TILE_A)), dim3(TP_T), 0, stream>>>(cls, clsT);
  }
  nms_kernel<<<dim3(B * N_CLS), dim3(NMS_T), 0, stream>>>(boxes, cls, clsT, picks, useT);
  topk_merge_kernel<<<dim3(B), dim3(512), 0, stream>>>(picks, boxes, (float*)d_out, B);
}